// Round 1
// baseline (1127.237 us; speedup 1.0000x reference)
//
#include <hip/hip_runtime.h>
#include <hip/hip_bf16.h>
#include <math.h>

#define BB 64
#define JJ 16384
#define DD 32
#define HH 128
#define WW 4
#define EHH 256
#define CHUNK 256
#define CPB 4
#define NBLK (JJ / (CHUNK * CPB)) /* 16 */
#define PART_STRIDE 136
#define LN_EPS 1e-5f

// ---------------- Kernel 1: fused row-MLP + chunked online masked softmax ----------------
__launch_bounds__(256, 2)
__global__ void pe_k1(const float* __restrict__ x, const int* __restrict__ mask,
                      const float* __restrict__ feat,
                      const float* __restrict__ w1, const float* __restrict__ b1,
                      const float* __restrict__ ln1g, const float* __restrict__ ln1b,
                      const float* __restrict__ w2, const float* __restrict__ b2,
                      const float* __restrict__ ln2g, const float* __restrict__ ln2b,
                      const float* __restrict__ gw1, const float* __restrict__ gb1,
                      const float* __restrict__ gw2, const float* __restrict__ gb2,
                      float* __restrict__ part)
{
    const int tid = threadIdx.x;
    const int cb = blockIdx.x, b = blockIdx.y;

    __shared__ float rowbuf[CHUNK][33];   // feat staging, then h_out per row
    __shared__ float p_lds[CHUNK][5];     // softmax numerators (padded stride 5)
    __shared__ float red_m[16];           // 4 waves x 4 heads (max)
    __shared__ float red_s[16];           // 4 waves x 4 heads (sum)

    const int wv = tid >> 6, lane = tid & 63;
    const int aw = tid >> 5, ad = tid & 31;   // accumulate mapping (tid<128)

    float m_run = -1e30f, s_run = 0.f, accr = 0.f;

    for (int ch = 0; ch < CPB; ++ch) {
        const int jbase = (cb * CPB + ch) * CHUNK;

        // ---- stage feat rows for this chunk into LDS (coalesced, padded 33) ----
        #pragma unroll
        for (int i = 0; i < 32; ++i) {
            int idx = i * CHUNK + tid;
            rowbuf[idx >> 5][idx & 31] = feat[jbase * 32 + idx];
        }
        __syncthreads();

        const int j = jbase + tid;
        const float xin = x[(size_t)b * JJ + j];
        const float maskf = mask[(size_t)b * JJ + j] ? 1.f : 0.f;

        // ---- stage 1: (1+32) -> 128 ----
        float hb[HH];
        #pragma unroll
        for (int o = 0; o < HH; ++o) hb[o] = b1[o];
        #pragma unroll
        for (int o = 0; o < HH; ++o) hb[o] = fmaf(w1[o], xin, hb[o]);
        for (int k = 1; k < 33; ++k) {
            const float f = rowbuf[tid][k - 1];
            const float* wr = w1 + k * HH;
            #pragma unroll
            for (int o = 0; o < HH; ++o) hb[o] = fmaf(wr[o], f, hb[o]);
        }
        // LN1 + relu
        {
            float s0=0,s1=0,s2=0,s3=0,q0=0,q1=0,q2=0,q3=0;
            #pragma unroll
            for (int o = 0; o < HH; o += 4) {
                s0 += hb[o];   s1 += hb[o+1]; s2 += hb[o+2]; s3 += hb[o+3];
                q0 = fmaf(hb[o],hb[o],q0);     q1 = fmaf(hb[o+1],hb[o+1],q1);
                q2 = fmaf(hb[o+2],hb[o+2],q2); q3 = fmaf(hb[o+3],hb[o+3],q3);
            }
            const float mu = (s0+s1+s2+s3) * (1.f/HH);
            float var = (q0+q1+q2+q3) * (1.f/HH) - mu*mu;
            var = fmaxf(var, 0.f);
            const float rs = rsqrtf(var + LN_EPS);
            #pragma unroll
            for (int o = 0; o < HH; ++o)
                hb[o] = fmaxf(fmaf((hb[o]-mu)*rs, ln1g[o], ln1b[o]), 0.f);
        }

        // ---- stage 2: 128 -> 32 (stream outputs through own LDS row) ----
        float sum2 = 0.f, sq2 = 0.f;
        #pragma unroll 2
        for (int d = 0; d < DD; ++d) {
            float a0 = b2[d], a1 = 0.f, a2 = 0.f, a3 = 0.f;
            const float* wc = w2 + d;
            #pragma unroll
            for (int k = 0; k < HH; k += 4) {
                a0 = fmaf(hb[k],   wc[(k  )*DD], a0);
                a1 = fmaf(hb[k+1], wc[(k+1)*DD], a1);
                a2 = fmaf(hb[k+2], wc[(k+2)*DD], a2);
                a3 = fmaf(hb[k+3], wc[(k+3)*DD], a3);
            }
            const float v = (a0+a1)+(a2+a3);
            rowbuf[tid][d] = v;          // own row only: no cross-thread hazard
            sum2 += v; sq2 = fmaf(v, v, sq2);
        }
        float ho[DD];
        {
            const float mu = sum2 * (1.f/DD);
            float var = sq2 * (1.f/DD) - mu*mu;
            var = fmaxf(var, 0.f);
            const float rs = rsqrtf(var + LN_EPS);
            #pragma unroll
            for (int d = 0; d < DD; ++d) {
                float v = rowbuf[tid][d];
                v = fmaxf(fmaf((v-mu)*rs, ln2g[d], ln2b[d]), 0.f);
                ho[d] = v;
                rowbuf[tid][d] = v;      // h_out for the weighted-sum phase
            }
        }

        // ---- stage 3: 32 -> 16 relu ----
        float g1v[16];
        #pragma unroll
        for (int o = 0; o < 16; ++o) g1v[o] = gb1[o];
        #pragma unroll
        for (int k = 0; k < DD; ++k) {
            #pragma unroll
            for (int o = 0; o < 16; ++o) g1v[o] = fmaf(ho[k], gw1[k*16+o], g1v[o]);
        }
        #pragma unroll
        for (int o = 0; o < 16; ++o) g1v[o] = fmaxf(g1v[o], 0.f);

        // ---- stage 4: 16 -> 4, clip ----
        float lg[WW];
        #pragma unroll
        for (int w = 0; w < WW; ++w) lg[w] = gb2[w];
        #pragma unroll
        for (int k = 0; k < 16; ++k) {
            #pragma unroll
            for (int w = 0; w < WW; ++w) lg[w] = fmaf(g1v[k], gw2[k*WW+w], lg[w]);
        }
        #pragma unroll
        for (int w = 0; w < WW; ++w) lg[w] = fminf(fmaxf(lg[w], -10.f), 10.f);

        // ---- chunk masked max (wave shfl + LDS combine) ----
        float lm[WW];
        #pragma unroll
        for (int w = 0; w < WW; ++w) lm[w] = (maskf > 0.f) ? lg[w] : -1e30f;
        #pragma unroll
        for (int off = 32; off > 0; off >>= 1) {
            #pragma unroll
            for (int w = 0; w < WW; ++w) lm[w] = fmaxf(lm[w], __shfl_xor(lm[w], off, 64));
        }
        if (lane == 0) {
            #pragma unroll
            for (int w = 0; w < WW; ++w) red_m[wv*4+w] = lm[w];
        }
        __syncthreads();
        float m_c[WW];
        #pragma unroll
        for (int w = 0; w < WW; ++w)
            m_c[w] = fmaxf(fmaxf(red_m[w], red_m[4+w]), fmaxf(red_m[8+w], red_m[12+w]));

        // ---- p = mask * exp(l - m_c); chunk sums ----
        float pv[WW];
        #pragma unroll
        for (int w = 0; w < WW; ++w) {
            pv[w] = maskf * __expf(fminf(lg[w] - m_c[w], 0.f));
            p_lds[tid][w] = pv[w];
        }
        float ps[WW];
        #pragma unroll
        for (int w = 0; w < WW; ++w) ps[w] = pv[w];
        #pragma unroll
        for (int off = 32; off > 0; off >>= 1) {
            #pragma unroll
            for (int w = 0; w < WW; ++w) ps[w] += __shfl_xor(ps[w], off, 64);
        }
        if (lane == 0) {
            #pragma unroll
            for (int w = 0; w < WW; ++w) red_s[wv*4+w] = ps[w];
        }
        __syncthreads();

        // ---- online merge of this chunk into running (m,s,acc) ----
        if (tid < 128) {
            const float s_c = red_s[aw] + red_s[4+aw] + red_s[8+aw] + red_s[12+aw];
            const float mc = m_c[aw];
            const float mn = fmaxf(m_run, mc);
            const float ea = __expf(m_run - mn);
            const float eb = __expf(mc - mn);
            float dot = 0.f;
            #pragma unroll 4
            for (int jj = 0; jj < CHUNK; ++jj)
                dot = fmaf(p_lds[jj][aw], rowbuf[jj][ad], dot);
            accr  = fmaf(accr,  ea, dot * eb);
            s_run = fmaf(s_run, ea, s_c * eb);
            m_run = mn;
        }
        __syncthreads();
    }

    if (tid < 128) {
        float* pp = part + (size_t)(b * NBLK + cb) * PART_STRIDE;
        if (ad == 0) { pp[aw] = m_run; pp[4 + aw] = s_run; }
        pp[8 + aw*32 + ad] = accr;
    }
}

// ---------------- Kernel 2: merge partials + per-batch encoder head ----------------
__global__ void pe_k2(const float* __restrict__ part,
                      const float* __restrict__ cw, const float* __restrict__ cb_,
                      const float* __restrict__ cg, const float* __restrict__ cbn,
                      const float* __restrict__ ew1, const float* __restrict__ eb1,
                      const float* __restrict__ eg1, const float* __restrict__ ebn1,
                      const float* __restrict__ ew2, const float* __restrict__ eb2,
                      const float* __restrict__ eg2, const float* __restrict__ ebn2,
                      float* __restrict__ out)
{
    const int b = blockIdx.x, tid = threadIdx.x;
    const int w = tid >> 5, d = tid & 31;
    __shared__ float hs[128];
    __shared__ float cbuf[32];
    __shared__ float ebuf[256];
    __shared__ float obuf[64];

    // merge per-block online-softmax partials
    float m = -1e30f, s = 0.f, a = 0.f;
    for (int c = 0; c < NBLK; ++c) {
        const float* pp = part + (size_t)(b * NBLK + c) * PART_STRIDE;
        const float mc = pp[w], sc = pp[4 + w], ac = pp[8 + w*32 + d];
        const float mn = fmaxf(m, mc);
        const float e0 = __expf(m - mn), e1v = __expf(mc - mn);
        a = fmaf(a, e0, ac * e1v);
        s = fmaf(s, e0, sc * e1v);
        m = mn;
    }
    hs[w*32 + d] = a / fmaxf(s, 1e-30f);
    const bool has = (s > 0.f);
    __syncthreads();

    // combined = relu(LN(hs @ c_w + c_b)); c = has ? combined : 0
    if (tid < 32) {
        float acc = cb_[tid];
        for (int k = 0; k < 128; ++k) acc = fmaf(hs[k], cw[k*32 + tid], acc);
        cbuf[tid] = acc;
    }
    __syncthreads();
    {
        float mu = 0.f, sq = 0.f;
        for (int k = 0; k < 32; ++k) { float v = cbuf[k]; mu += v; sq = fmaf(v, v, sq); }
        mu *= (1.f/32);
        float var = fmaxf(sq*(1.f/32) - mu*mu, 0.f);
        const float rs = rsqrtf(var + LN_EPS);
        __syncthreads();
        if (tid < 32) {
            float v = (cbuf[tid] - mu) * rs;
            v = fmaxf(fmaf(v, cg[tid], cbn[tid]), 0.f);
            cbuf[tid] = has ? v : 0.f;
        }
    }
    __syncthreads();

    // e1 = relu(LN(c @ e_w1 + e_b1))   (32 -> 256)
    #pragma unroll
    for (int r = 0; r < 2; ++r) {
        const int o = tid + r*128;
        float acc = eb1[o];
        for (int k = 0; k < 32; ++k) acc = fmaf(cbuf[k], ew1[k*EHH + o], acc);
        ebuf[o] = acc;
    }
    __syncthreads();
    {
        float mu = 0.f, sq = 0.f;
        for (int k = 0; k < 256; ++k) { float v = ebuf[k]; mu += v; sq = fmaf(v, v, sq); }
        mu *= (1.f/256);
        float var = fmaxf(sq*(1.f/256) - mu*mu, 0.f);
        const float rs = rsqrtf(var + LN_EPS);
        __syncthreads();
        #pragma unroll
        for (int r = 0; r < 2; ++r) {
            const int o = tid + r*128;
            float v = (ebuf[o] - mu) * rs;
            ebuf[o] = fmaxf(fmaf(v, eg1[o], ebn1[o]), 0.f);
        }
    }
    __syncthreads();

    // mu_logvar = relu(LN(e1 @ e_w2 + e_b2))  (256 -> 64), split and store
    if (tid < 64) {
        float acc = eb2[tid];
        for (int k = 0; k < 256; ++k) acc = fmaf(ebuf[k], ew2[k*64 + tid], acc);
        obuf[tid] = acc;
    }
    __syncthreads();
    {
        float mu = 0.f, sq = 0.f;
        for (int k = 0; k < 64; ++k) { float v = obuf[k]; mu += v; sq = fmaf(v, v, sq); }
        mu *= (1.f/64);
        float var = fmaxf(sq*(1.f/64) - mu*mu, 0.f);
        const float rs = rsqrtf(var + LN_EPS);
        if (tid < 64) {
            float v = (obuf[tid] - mu) * rs;
            v = fmaxf(fmaf(v, eg2[tid], ebn2[tid]), 0.f);
            if (tid < 32) out[(size_t)b*32 + tid] = v;                    // mu
            else          out[(size_t)BB*32 + (size_t)b*32 + (tid-32)] = v; // logvar
        }
    }
}

extern "C" void kernel_launch(void* const* d_in, const int* in_sizes, int n_in,
                              void* d_out, int out_size, void* d_ws, size_t ws_size,
                              hipStream_t stream) {
    (void)in_sizes; (void)n_in; (void)out_size; (void)ws_size;
    const float* x     = (const float*)d_in[0];
    const int*   mask  = (const int*)  d_in[1];
    const float* feat  = (const float*)d_in[2];
    const float* h_w1  = (const float*)d_in[3];
    const float* h_b1  = (const float*)d_in[4];
    const float* h_l1g = (const float*)d_in[5];
    const float* h_l1b = (const float*)d_in[6];
    const float* h_w2  = (const float*)d_in[7];
    const float* h_b2  = (const float*)d_in[8];
    const float* h_l2g = (const float*)d_in[9];
    const float* h_l2b = (const float*)d_in[10];
    const float* g_w1  = (const float*)d_in[11];
    const float* g_b1  = (const float*)d_in[12];
    const float* g_w2  = (const float*)d_in[13];
    const float* g_b2  = (const float*)d_in[14];
    const float* c_w   = (const float*)d_in[15];
    const float* c_b   = (const float*)d_in[16];
    const float* c_lg  = (const float*)d_in[17];
    const float* c_lb  = (const float*)d_in[18];
    const float* e_w1  = (const float*)d_in[19];
    const float* e_b1  = (const float*)d_in[20];
    const float* e_l1g = (const float*)d_in[21];
    const float* e_l1b = (const float*)d_in[22];
    const float* e_w2  = (const float*)d_in[23];
    const float* e_b2  = (const float*)d_in[24];
    const float* e_l2g = (const float*)d_in[25];
    const float* e_l2b = (const float*)d_in[26];

    float* part = (float*)d_ws;
    float* out  = (float*)d_out;

    dim3 g1(NBLK, BB);
    pe_k1<<<g1, dim3(256), 0, stream>>>(x, mask, feat,
                                        h_w1, h_b1, h_l1g, h_l1b,
                                        h_w2, h_b2, h_l2g, h_l2b,
                                        g_w1, g_b1, g_w2, g_b2, part);
    pe_k2<<<dim3(BB), dim3(128), 0, stream>>>(part,
                                              c_w, c_b, c_lg, c_lb,
                                              e_w1, e_b1, e_l1g, e_l1b,
                                              e_w2, e_b2, e_l2g, e_l2b, out);
}